// Round 12
// baseline (213.268 us; speedup 1.0000x reference)
//
#include <hip/hip_runtime.h>
#include <math.h>

// B=4, C=256, N=H*W=4096, G=32. All inputs/output FLOAT32; bf16 internally.
// out = x + nin3( attn( nin0/1/2( groupnorm(x) ) ) )
//
// R20: attn sync rebuilt as counted-vmcnt + two RAW barriers (T3/T4 pattern):
//   STAGE(i+1); vmcnt(8|0); s_barrier; QK/SM/PV(i); s_barrier
// vs R19's single __syncthreads whose vmcnt(0) drain stalled all waves AND
// delayed the next STAGE issue (prefetch depth collapsed to 1 at each
// barrier). Now STAGE(i+2) is issued BEFORE the tile-(i+1) wait -> the
// drain stall overlaps new fetch traffic. RAW: per-wave vmcnt THEN barrier
// (barrier release => all waves' tile-i DMAs landed). WAR: B2 separates
// reads from next STAGE's writes. Bit-identical values if race-free.
// Everything outside ATTN_STEP byte-identical to R19 (210.7us pass).

typedef short short8    __attribute__((ext_vector_type(8)));
typedef ushort ushort8  __attribute__((ext_vector_type(8)));
typedef ushort ushort4v __attribute__((ext_vector_type(4)));
typedef float f32x4     __attribute__((ext_vector_type(4)));
typedef float f32x16    __attribute__((ext_vector_type(16)));

#define BB 4
#define CCH 256
#define NSP 4096
#define TEN ((size_t)BB * NSP * CCH)

__device__ __forceinline__ float b2f(ushort h){
  unsigned int u = ((unsigned int)h) << 16;
  float f; __builtin_memcpy(&f, &u, 4); return f;
}
__device__ __forceinline__ ushort f2b(float f){
  unsigned int u; __builtin_memcpy(&u, &f, 4);
  u += 0x7fffu + ((u >> 16) & 1u);   // RTNE
  return (ushort)(u >> 16);
}
// HW packed f32->bf16 RTNE (identical result to f2b pair, 1 instr vs ~6)
__device__ __forceinline__ unsigned int pk2(float a, float b){
  unsigned int r;
  asm("v_cvt_pk_bf16_f32 %0, %1, %2" : "=&v"(r) : "v"(a), "v"(b));
  return r;
}
// async global->LDS DMA, 16B per lane; LDS dest = wave-uniform base + lane*16
__device__ __forceinline__ void dma16(const void* g, void* l){
  __builtin_amdgcn_global_load_lds((const __attribute__((address_space(1))) void*)g,
                                   (__attribute__((address_space(3))) void*)l,
                                   16, 0, 0);
}

// ------- fused: weight transpose+cast (bx<64) | GN partial sums (bx>=64) -------
__global__ __launch_bounds__(256) void pre_k(const float* __restrict__ x,
                                             const float* __restrict__ w0,
                                             const float* __restrict__ w1,
                                             const float* __restrict__ w2,
                                             const float* __restrict__ w3,
                                             ushort* __restrict__ wT,
                                             float* __restrict__ sums){
  __shared__ ushort tile[64][72];
  __shared__ float red[8];
  const int bxx = blockIdx.x;
  const int t = threadIdx.x;
  if (bxx < 64){
    const int wsel = bxx >> 4, tb = bxx & 15;
    const float* w = (wsel==0) ? w0 : (wsel==1) ? w1 : (wsel==2) ? w2 : w3;
    ushort* dst = wT + (size_t)wsel * 65536;
    const int r0 = (tb >> 2) * 64, c0 = (tb & 3) * 64;
    #pragma unroll
    for (int p = 0; p < 2; p++){
      const int r = p*32 + (t >> 3), cc = (t & 7)*8;
      const float* wr = w + (size_t)(r0 + r)*256 + c0 + cc;
      f32x4 a = *(const f32x4*)wr;
      f32x4 d = *(const f32x4*)(wr + 4);
      #pragma unroll
      for (int j = 0; j < 4; j++){
        tile[r][cc + j]     = f2b(a[j]);
        tile[r][cc + 4 + j] = f2b(d[j]);
      }
    }
    __syncthreads();
    #pragma unroll
    for (int p = 0; p < 2; p++){
      const int r = p*32 + (t >> 3), cc = (t & 7)*8;
      ushort8 ov;
      #pragma unroll
      for (int j = 0; j < 8; j++) ov[j] = tile[cc + j][r];
      *(ushort8*)(dst + (size_t)(c0 + r)*256 + r0 + cc) = ov;
    }
  } else {
    // q = (bg, half): each block sums half a group's 16384 floats
    const int q = bxx - 64;                 // 0..255
    const f32x4* p = (const f32x4*)(x + (size_t)(q >> 1)*32768 + (size_t)(q & 1)*16384);
    float s = 0.f, s2 = 0.f;
    for (int i = t; i < 4096; i += 256){
      f32x4 v = p[i];
      #pragma unroll
      for (int j = 0; j < 4; j++){ s += v[j]; s2 += v[j]*v[j]; }
    }
    #pragma unroll
    for (int off = 32; off >= 1; off >>= 1){
      s  += __shfl_down(s,  off, 64);
      s2 += __shfl_down(s2, off, 64);
    }
    const int w = t >> 6;
    if ((t & 63) == 0){ red[w*2] = s; red[w*2+1] = s2; }
    __syncthreads();
    if (t == 0){
      sums[q*2]   = red[0]+red[2]+red[4]+red[6];
      sums[q*2+1] = red[1]+red[3]+red[5]+red[7];
    }
  }
}

// ------- GN apply (finalizes stats from partial sums) + transpose + cast -------
__global__ __launch_bounds__(256) void gn_apply_k(const float* __restrict__ x,
                                                  const float* __restrict__ sums,
                                                  const float* __restrict__ gamma,
                                                  const float* __restrict__ beta,
                                                  ushort* __restrict__ h_t){
  __shared__ ushort tile[64][72];
  const int b = blockIdx.z, c0 = blockIdx.y*64, n0 = blockIdx.x*64;
  const int t = threadIdx.x;
  #pragma unroll
  for (int p = 0; p < 2; p++){
    const int cl = p*32 + (t >> 3);
    const int nc = (t & 7) * 8;
    const int c = c0 + cl;
    const int bg = b*32 + (c>>3);
    const float S  = sums[bg*4+0] + sums[bg*4+2];
    const float S2 = sums[bg*4+1] + sums[bg*4+3];
    const float mean = S * (1.f/32768.f);
    const float rstd = rsqrtf(fmaxf(S2*(1.f/32768.f) - mean*mean, 0.f) + 1e-6f);
    const float sc = rstd * gamma[c];
    const float sh = beta[c] - mean * sc;
    const float* xr = x + ((size_t)b*CCH + c)*NSP + n0 + nc;
    f32x4 a = *(const f32x4*)xr;
    f32x4 d = *(const f32x4*)(xr + 4);
    #pragma unroll
    for (int j = 0; j < 4; j++){
      tile[nc + j][cl]     = f2b(a[j]*sc + sh);
      tile[nc + 4 + j][cl] = f2b(d[j]*sc + sh);
    }
  }
  __syncthreads();
  #pragma unroll
  for (int p = 0; p < 2; p++){
    const int nl = p*32 + (t >> 3);
    const int cc = (t & 7) * 8;
    ushort8 ov;
    #pragma unroll
    for (int j = 0; j < 8; j++) ov[j] = tile[nl][cc + j];
    *(ushort8*)(h_t + ((size_t)b*NSP + n0 + nl)*CCH + c0 + cc) = ov;
  }
}

// ------------- merged QKV GEMMs: z=0 -> Q&K (Bt staged once, tm loop),
//               z=1 -> V (afr loaded once, tn loop) ---------------------------
// K output layout: Kg[b][tile(n>>5)][g=(m>>3)][key=(n&31)][8ch]   (attn cells)
// V output layout: Vg[b][tile(m>>5)][s=(m>>3)&3][c=n][8key]       (attn cells)
__global__ __launch_bounds__(256) void gemm_qkv_k(const ushort* __restrict__ wT,
                                                  const ushort* __restrict__ h_t,
                                                  ushort* __restrict__ q_t,
                                                  ushort* __restrict__ k_t,
                                                  ushort* __restrict__ vout,
                                                  const float* __restrict__ b0,
                                                  const float* __restrict__ b1,
                                                  const float* __restrict__ b2){
  __shared__ ushort Bt[64*256];
  const int K = 256;
  const long HS = (long)NSP * CCH;
  const int t = threadIdx.x, w = t >> 6, lane = t & 63;
  const int li = lane & 15, quad = lane >> 4;
  const int batch = blockIdx.y;

  if (blockIdx.z == 0){
    const ushort* Bm = h_t + (size_t)batch * HS;
    ushort* out0 = q_t + (size_t)batch * HS;
    ushort* out1 = k_t + (size_t)batch * HS;
    const int nb = blockIdx.x * 64;

    #pragma unroll
    for (int i = 0; i < 8; i++){
      const int id = t + 256*i;
      const int row = id >> 5, gg = id & 31;
      *(ushort8*)&Bt[row*256 + (gg ^ (row & 31))*8] =
        *(const ushort8*)(Bm + (size_t)(nb + row)*K + gg*8);
    }
    __syncthreads();

    for (int tm = 0; tm < 4; tm++){
      const int m0 = tm*64 + w*16;
      short8 afr0[8], afr1[8];
      #pragma unroll
      for (int kk = 0; kk < 8; kk++){
        afr0[kk] = *(const short8*)(wT +         (size_t)(m0 + li)*K + kk*32 + quad*8);
        afr1[kk] = *(const short8*)(wT + 65536 + (size_t)(m0 + li)*K + kk*32 + quad*8);
      }
      #pragma unroll
      for (int nt = 0; nt < 4; nt++){
        f32x4 acc0 = {0.f,0.f,0.f,0.f};
        f32x4 acc1 = {0.f,0.f,0.f,0.f};
        const int n = nb + nt*16 + li;
        const int rowl = nt*16 + li;
        #pragma unroll
        for (int kk = 0; kk < 8; kk++){
          short8 bfr = *(const short8*)&Bt[rowl*256 + ((4*kk + quad) ^ (rowl & 31))*8];
          acc0 = __builtin_amdgcn_mfma_f32_16x16x32_bf16(afr0[kk], bfr, acc0, 0, 0, 0);
          acc1 = __builtin_amdgcn_mfma_f32_16x16x32_bf16(afr1[kk], bfr, acc1, 0, 0, 0);
        }
        float e0[4], e1[4];
        #pragma unroll
        for (int r2 = 0; r2 < 4; r2++){
          e0[r2] = acc0[r2] + b0[m0 + quad*4 + r2];
          e1[r2] = acc1[r2] + b1[m0 + quad*4 + r2];
        }
        uint2 d0; d0.x = pk2(e0[0], e0[1]); d0.y = pk2(e0[2], e0[3]);
        uint2 d1; d1.x = pk2(e1[0], e1[1]); d1.y = pk2(e1[2], e1[3]);
        const int m = m0 + quad*4;
        *(uint2*)(out0 + (size_t)n*256 + m) = d0;                    // Q: n-major
        *(uint2*)(out1 + (size_t)(n >> 5)*8192 + (m >> 3)*256
                       + (n & 31)*8 + (m & 7)) = d1;                 // K: tiled
      }
    }
  } else {
    const ushort* A  = h_t + (size_t)batch * HS;
    const ushort* Bm = wT + 2*65536;
    ushort* OutT = vout + (size_t)batch * HS;
    const int m0 = blockIdx.x*64 + w*16;

    short8 afr[8];
    #pragma unroll
    for (int kk = 0; kk < 8; kk++)
      afr[kk] = *(const short8*)(A + (size_t)(m0 + li)*K + kk*32 + quad*8);

    for (int tn = 0; tn < 4; tn++){
      const int nb = tn*64;
      __syncthreads();
      #pragma unroll
      for (int i = 0; i < 8; i++){
        const int id = t + 256*i;
        const int row = id >> 5, gg = id & 31;
        *(ushort8*)&Bt[row*256 + (gg ^ (row & 31))*8] =
          *(const ushort8*)(Bm + (size_t)(nb + row)*K + gg*8);
      }
      __syncthreads();

      #pragma unroll
      for (int nt = 0; nt < 4; nt++){
        f32x4 acc = {0.f,0.f,0.f,0.f};
        const int n = nb + nt*16 + li;
        const int rowl = nt*16 + li;
        #pragma unroll
        for (int kk = 0; kk < 8; kk++){
          short8 bfr = *(const short8*)&Bt[rowl*256 + ((4*kk + quad) ^ (rowl & 31))*8];
          acc = __builtin_amdgcn_mfma_f32_16x16x32_bf16(afr[kk], bfr, acc, 0, 0, 0);
        }
        const float bn = b2[n];
        float e[4];
        #pragma unroll
        for (int r2 = 0; r2 < 4; r2++) e[r2] = acc[r2] + bn;
        uint2 dv; dv.x = pk2(e[0], e[1]); dv.y = pk2(e[2], e[3]);
        const int m = m0 + quad*4;                                   // spatial key
        *(uint2*)(OutT + (size_t)(m >> 5)*8192 + ((m >> 3) & 3)*2048
                       + (size_t)n*8 + (m & 7)) = dv;                // V: tiled
      }
    }
  }
}

// ---------------- 32x32x16 fixed-M flash attention, full-DMA double-buffer -----
// R20 sync: STAGE(i+1); vmcnt(8|0); s_barrier(B1); compute(i); s_barrier(B2).
// RAW: per-wave counted vmcnt THEN barrier => all waves' tile-i DMAs landed.
// WAR: B2 separates tile-i reads from iter i+1's STAGE writes into buf[cur].
#define STAGE_KV(KDST, VDST, TILE)                                              \
  _Pragma("unroll")                                                             \
  for (int i_ = 0; i_ < 4; i_++){                                               \
    const int cell_ = (w*4 + i_)*64 + lane;                                     \
    dma16(kb + (size_t)(TILE)*8192 + cell_*8, &(KDST)[(w*4 + i_)*512]);         \
    dma16(vb + (size_t)(TILE)*8192 + cell_*8, &(VDST)[(w*4 + i_)*512]);         \
  }

#define ATTN_STEP(KC, VC, KN, VN, IT)                                           \
  {                                                                             \
    const int it_ = (IT);                                                       \
    const bool more_ = (it_ + 1 < iters);                                       \
    if (more_){                                                                 \
      STAGE_KV(KN, VN, tile0 + it_ + 1);                                        \
      asm volatile("s_waitcnt vmcnt(8)" ::: "memory");                          \
    } else {                                                                    \
      asm volatile("s_waitcnt vmcnt(0)" ::: "memory");                          \
    }                                                                           \
    __builtin_amdgcn_sched_barrier(0);                                          \
    __builtin_amdgcn_s_barrier();        /* B1: tile-i DMAs visible to all */   \
    f32x16 sacc = (f32x16)(0.f);                                                \
    _Pragma("unroll")                                                           \
    for (int st = 0; st < 16; st++){                                            \
      short8 kf = *(const short8*)&(KC)[((st*2 + h)*32 + cl)*8];                \
      sacc = __builtin_amdgcn_mfma_f32_32x32x16_bf16(kf, qf[st], sacc, 0, 0, 0);\
    }                                                                           \
    unsigned int grp[4][2];                                                     \
    _Pragma("unroll")                                                           \
    for (int m = 0; m < 4; m++){                                                \
      float p0 = __builtin_amdgcn_exp2f(fminf(sacc[4*m+0]*c1 - M2, 30.f));      \
      float p1 = __builtin_amdgcn_exp2f(fminf(sacc[4*m+1]*c1 - M2, 30.f));      \
      float p2 = __builtin_amdgcn_exp2f(fminf(sacc[4*m+2]*c1 - M2, 30.f));      \
      float p3 = __builtin_amdgcn_exp2f(fminf(sacc[4*m+3]*c1 - M2, 30.f));      \
      l_i += (p0 + p1) + (p2 + p3);                                             \
      grp[m][0] = pk2(p0, p1);                                                  \
      grp[m][1] = pk2(p2, p3);                                                  \
    }                                                                           \
    unsigned int sa0 = h ? grp[0][0] : grp[1][0];                               \
    unsigned int sa1 = h ? grp[0][1] : grp[1][1];                               \
    unsigned int sb0 = h ? grp[2][0] : grp[3][0];                               \
    unsigned int sb1 = h ? grp[2][1] : grp[3][1];                               \
    unsigned int ra0 = __shfl_xor((int)sa0, 32, 64);                            \
    unsigned int ra1 = __shfl_xor((int)sa1, 32, 64);                            \
    unsigned int rb0 = __shfl_xor((int)sb0, 32, 64);                            \
    unsigned int rb1 = __shfl_xor((int)sb1, 32, 64);                            \
    unsigned int f0[4], f1[4];                                                  \
    if (h == 0){                                                                \
      f0[0]=grp[0][0]; f0[1]=grp[0][1]; f0[2]=ra0; f0[3]=ra1;                   \
      f1[0]=grp[2][0]; f1[1]=grp[2][1]; f1[2]=rb0; f1[3]=rb1;                   \
    } else {                                                                    \
      f0[0]=ra0; f0[1]=ra1; f0[2]=grp[1][0]; f0[3]=grp[1][1];                   \
      f1[0]=rb0; f1[1]=rb1; f1[2]=grp[3][0]; f1[3]=grp[3][1];                   \
    }                                                                           \
    short8 pf0, pf1;                                                            \
    __builtin_memcpy(&pf0, f0, 16);                                             \
    __builtin_memcpy(&pf1, f1, 16);                                             \
    _Pragma("unroll")                                                           \
    for (int ct = 0; ct < 8; ct++){                                             \
      short8 v0 = *(const short8*)&(VC)[(h*256 + ct*32 + cl)*8];                \
      short8 v1 = *(const short8*)&(VC)[((2 + h)*256 + ct*32 + cl)*8];          \
      oacc[ct] = __builtin_amdgcn_mfma_f32_32x32x16_bf16(pf0, v0, oacc[ct], 0, 0, 0); \
      oacc[ct] = __builtin_amdgcn_mfma_f32_32x32x16_bf16(pf1, v1, oacc[ct], 0, 0, 0); \
    }                                                                           \
    if (more_) __builtin_amdgcn_s_barrier();  /* B2: reads done before next STAGE */ \
  }

__global__ __launch_bounds__(256, 2) void attn32_k(const ushort* __restrict__ qg,
                                                   const ushort* __restrict__ kg,
                                                   const ushort* __restrict__ vg,
                                                   ushort* __restrict__ ph01,
                                                   ushort* __restrict__ ph23,
                                                   float* __restrict__ lbuf,
                                                   int iters, int ks4){
  __shared__ ushort KtA[8192], KtB[8192];  // [g(32)][key(32)] x 8 ushort
  __shared__ ushort VtA[8192], VtB[8192];  // [s(4)][c(256)] x 8 ushort

  const int t = threadIdx.x, lane = t & 63;
  const int cl = lane & 31, h = lane >> 5;
  const int bx = blockIdx.x;
  const int qt = bx / ks4;                 // ks4 = 4*ks
  const int r  = bx % ks4;
  const int s  = r >> 2, b = r & 3;
  const int n0 = qt * 128;
  const int w = t >> 6;
  const int qb = n0 + w*32;                // wave's query base
  const int keybase = s * (iters * 32);
  const int tile0 = keybase >> 5;

  const ushort* kb = kg + (size_t)b*NSP*CCH;
  const ushort* vb = vg + (size_t)b*CCH*NSP;

  // Q as B-operand: lane holds q = qb+cl, channels st*16 + h*8 + j
  short8 qf[16];
  {
    const ushort* qrow = qg + ((size_t)b*NSP + qb + cl)*CCH + h*8;
    #pragma unroll
    for (int st = 0; st < 16; st++) qf[st] = *(const short8*)(qrow + st*16);
  }

  f32x16 oacc[8];
  #pragma unroll
  for (int i = 0; i < 8; i++) oacc[i] = (f32x16)(0.f);
  float l_i = 0.f;
  const float c1 = 0.0625f * 1.44269504088896f;   // C^-0.5 * log2(e)
  const float M2 = 24.f;

  // prologue: DMA tile 0 into A buffers; full drain once (tile 0 visible)
  STAGE_KV(KtA, VtA, tile0);
  __syncthreads();

  for (int it = 0; it < iters; it += 2){   // iters even (32 or 64)
    ATTN_STEP(KtA, VtA, KtB, VtB, it);
    ATTN_STEP(KtB, VtB, KtA, VtA, it + 1);
  }

  // partial store: PhT[s][b][c][q] (lane holds col c = ct*32+cl, 16 q rows)
  ushort* ps = (s < 2) ? (ph01 + (size_t)s*TEN) : (ph23 + (size_t)(s-2)*TEN);
  ps += (size_t)b * NSP * CCH;
  #pragma unroll
  for (int ct = 0; ct < 8; ct++){
    const size_t crow = (size_t)(ct*32 + cl) * NSP;
    #pragma unroll
    for (int m = 0; m < 4; m++){
      unsigned int d0 = pk2(oacc[ct][4*m+0], oacc[ct][4*m+1]);
      unsigned int d1 = pk2(oacc[ct][4*m+2], oacc[ct][4*m+3]);
      uint2 dv; dv.x = d0; dv.y = d1;
      *(uint2*)(ps + crow + qb + 8*m + 4*h) = dv;
    }
  }
  l_i += __shfl_xor(l_i, 32, 64);
  if (h == 0)
    lbuf[(size_t)s*BB*NSP + (size_t)b*NSP + qb + cl] = l_i;
}

// ---- fused combine + projection: 32q x 256d per block ------------------------
__global__ __launch_bounds__(256) void proj_comb_k(const ushort* __restrict__ ph01,
                                                   const ushort* __restrict__ ph23,
                                                   const float* __restrict__ lbuf,
                                                   const ushort* __restrict__ Bm,
                                                   const float* __restrict__ b3,
                                                   const float* __restrict__ xin,
                                                   float* __restrict__ out, int ks){
  __shared__ ushort At[32*256];            // normalized O tile, swizzled
  __shared__ ushort Bt[64*256];            // w3T d-tile
  const int K = 256;
  const int t = threadIdx.x, w = t >> 6, lane = t & 63;
  const int li = lane & 15, quad = lane >> 4;
  const int q0 = blockIdx.x * 32, b = blockIdx.y;

  // ---- combine phase ----
  const int ql4 = (t & 7) * 4;             // this thread's 4 queries
  const int cs  = t >> 3;                  // 32 c-slices of 8 channels
  float rl[4];
  #pragma unroll
  for (int j = 0; j < 4; j++){
    float suml = 0.f;
    for (int sp = 0; sp < ks; sp++)
      suml += lbuf[(size_t)sp*BB*NSP + (size_t)b*NSP + q0 + ql4 + j];
    rl[j] = 1.f / suml;
  }
  #pragma unroll
  for (int ci = 0; ci < 8; ci++){
    const int c = cs*8 + ci;
    float acc[4] = {0.f, 0.f, 0.f, 0.f};
    for (int sp = 0; sp < ks; sp++){
      const ushort* pp = (sp < 2) ? (ph01 + (size_t)sp*TEN) : (ph23 + (size_t)(sp-2)*TEN);
      ushort4v u = *(const ushort4v*)(pp + ((size_t)b*CCH + c)*NSP + q0 + ql4);
      #pragma unroll
      for (int j = 0; j < 4; j++) acc[j] += b2f(u[j]);
    }
    const int g = c >> 3, co = c & 7;
    #pragma unroll
    for (int j = 0; j < 4; j++){
      const int row = ql4 + j;
      At[row*256 + ((g ^ row) & 31)*8 + co] = f2b(acc[j] * rl[j]);
    }
  }
  __syncthreads();

  // ---- GEMM phase: A from At (wave m-tile = w&1), d-halves by w>>1 ----
  const int mrow = (w & 1)*16 + li;
  short8 afr[8];
  #pragma unroll
  for (int kk = 0; kk < 8; kk++)
    afr[kk] = *(const short8*)&At[mrow*256 + (((4*kk + quad) ^ mrow) & 31)*8];

  xin += (size_t)b * CCH * NSP;
  out += (size_t)b * CCH * NSP;
  for (int tn = 0; tn < 4; tn++){
    __syncthreads();                       // prior Bt readers done
    #pragma unroll
    for (int i = 0; i < 8; i++){
      const int id = t + 256*i;
      const int row = id >> 5, gg = id & 31;
      *(ushort8*)&Bt[row*256 + (gg ^ (row & 31))*8] =
        *(const ushort8*)(Bm + (size_t)(tn*64 + row)*K + gg*8);
    }
    __syncthreads();                       // staged

    #pragma unroll
    for (int s2 = 0; s2 < 2; s2++){
      f32x4 acc = {0.f,0.f,0.f,0.f};
      const int rowb = (w >> 1)*32 + s2*16 + li;   // d row within 64-d tile
      const int d = tn*64 + rowb;
      #pragma unroll
      for (int kk = 0; kk < 8; kk++){
        short8 bfr = *(const short8*)&Bt[rowb*256 + (((4*kk + quad) ^ rowb) & 31)*8];
        acc = __builtin_amdgcn_mfma_f32_16x16x32_bf16(afr[kk], bfr, acc, 0, 0, 0);
      }
      const float bias = b3[d];
      const size_t idx = (size_t)d*NSP + q0 + (w & 1)*16 + quad*4;
      f32x4 xv = *(const f32x4*)(xin + idx);
      f32x4 ov;
      #pragma unroll
      for (int r2 = 0; r2 < 4; r2++) ov[r2] = acc[r2] + bias + xv[r2];
      *(f32x4*)(out + idx) = ov;
    }
  }
}

// ---------------- fallback: combine + proj as separate kernels -----------------
__global__ __launch_bounds__(256) void combine_k(const ushort* __restrict__ ph01,
                                                 const ushort* __restrict__ ph23,
                                                 const float* __restrict__ lbuf,
                                                 ushort* __restrict__ Oc, int ks){
  __shared__ ushort T[64*66];
  const int t = threadIdx.x;
  const int q0 = blockIdx.x * 64, c0 = blockIdx.y * 64, b = blockIdx.z;
  const int ql4 = (t & 15) * 4;
  const int cs  = t >> 4;
  float rl[4];
  #pragma unroll
  for (int j = 0; j < 4; j++){
    float suml = 0.f;
    for (int sp = 0; sp < ks; sp++)
      suml += lbuf[(size_t)sp*BB*NSP + (size_t)b*NSP + q0 + ql4 + j];
    rl[j] = 1.f / suml;
  }
  #pragma unroll
  for (int ci = 0; ci < 4; ci++){
    const int c = cs*4 + ci;
    float acc[4] = {0.f, 0.f, 0.f, 0.f};
    for (int sp = 0; sp < ks; sp++){
      const ushort* pp = (sp < 2) ? (ph01 + (size_t)sp*TEN) : (ph23 + (size_t)(sp-2)*TEN);
      ushort4v u = *(const ushort4v*)(pp + ((size_t)b*CCH + c0 + c)*NSP + q0 + ql4);
      #pragma unroll
      for (int j = 0; j < 4; j++) acc[j] += b2f(u[j]);
    }
    #pragma unroll
    for (int j = 0; j < 4; j++)
      T[(ql4 + j)*66 + c] = f2b(acc[j] * rl[j]);
  }
  __syncthreads();
  const int q2 = t >> 2, ch = (t & 3) * 16;
  ushort8 o0, o1;
  #pragma unroll
  for (int j = 0; j < 8; j++){ o0[j] = T[q2*66 + ch + j]; o1[j] = T[q2*66 + ch + 8 + j]; }
  ushort* dst = Oc + ((size_t)b*NSP + q0 + q2)*CCH + c0 + ch;
  *(ushort8*)dst = o0;
  *(ushort8*)(dst + 8) = o1;
}

__global__ __launch_bounds__(256) void gemm_proj_k(const ushort* __restrict__ A,
                                                   const ushort* __restrict__ Bm,
                                                   const float* __restrict__ b3,
                                                   const float* __restrict__ xin,
                                                   float* __restrict__ out){
  __shared__ ushort Bt[64*256];
  const int K = 256;
  const int t = threadIdx.x, w = t >> 6, lane = t & 63;
  const int li = lane & 15, quad = lane >> 4;
  const int tm = blockIdx.x & 63, tn = blockIdx.x >> 6;
  const int batch = blockIdx.y;
  A   += (size_t)batch * NSP * CCH;
  xin += (size_t)batch * CCH * NSP;
  out += (size_t)batch * CCH * NSP;
  const int m0 = tm*64 + w*16;
  const int nb = tn*64;

  #pragma unroll
  for (int i = 0; i < 8; i++){
    const int id = t + 256*i;
    const int row = id >> 5, gg = id & 31;
    *(ushort8*)&Bt[row*256 + (gg ^ (row & 31))*8] =
      *(const ushort8*)(Bm + (size_t)(nb + row)*K + gg*8);
  }
  short8 afr[8];
  #pragma unroll
  for (int kk = 0; kk < 8; kk++)
    afr[kk] = *(const short8*)(A + (size_t)(m0 + li)*K + kk*32 + quad*8);
  __syncthreads();

  #pragma unroll
  for (int nt = 0; nt < 4; nt++){
    f32x4 acc = {0.f,0.f,0.f,0.f};
    const int d = nb + nt*16 + li;
    const int rowl = nt*16 + li;
    #pragma unroll
    for (int kk = 0; kk < 8; kk++){
      short8 bfr = *(const short8*)&Bt[rowl*256 + ((4*kk + quad) ^ (rowl & 31))*8];
      acc = __builtin_amdgcn_mfma_f32_16x16x32_bf16(afr[kk], bfr, acc, 0, 0, 0);
    }
    const float bias = b3[d];
    const size_t idx = (size_t)d*NSP + m0 + quad*4;
    f32x4 xv = *(const f32x4*)(xin + idx);
    f32x4 ov;
    #pragma unroll
    for (int r = 0; r < 4; r++) ov[r] = acc[r] + bias + xv[r];
    *(f32x4*)(out + idx) = ov;
  }
}

extern "C" void kernel_launch(void* const* d_in, const int* in_sizes, int n_in,
                              void* d_out, int out_size, void* d_ws, size_t ws_size,
                              hipStream_t stream){
  const float* x     = (const float*)d_in[0];
  const float* gamma = (const float*)d_in[1];
  const float* beta  = (const float*)d_in[2];
  const float* w0    = (const float*)d_in[3];
  const float* b0    = (const float*)d_in[4];
  const float* w1    = (const float*)d_in[5];
  const float* b1    = (const float*)d_in[6];
  const float* w2    = (const float*)d_in[7];
  const float* b2    = (const float*)d_in[8];
  const float* w3    = (const float*)d_in[9];
  const float* b3    = (const float*)d_in[10];
  float* out = (float*)d_out;

  ushort* h_t  = (ushort*)d_out;                  // d_out scratch (dead later)
  ushort* q_t = (ushort*)d_ws;
  ushort* k_t = q_t + TEN;
  ushort* v   = k_t + TEN;
  ushort* wT  = v + TEN;                          // 4 x 65536 bf16
  float* sums  = (float*)(wT + 4*65536);          // 512 f32: GN partial sums
  float* lbuf  = sums + 512;                      // disjoint from sums
  ushort* phA = (ushort*)(lbuf + 4*BB*NSP);       // 2 splits (16.8 MB)
  ushort* phB = phA + 2*TEN;                      // 2 more splits (fused only)

  const size_t need4 = ((3*TEN + 4*65536)*2) + (512 + 4*BB*NSP)*4 + 2*TEN*2;
  const size_t need5 = need4 + 2*TEN*2;           // + ph01 in ws
  const int ks = (ws_size >= need4) ? 4 : 2;
  const int fused = (ws_size >= need5) && (ks == 4);
  const int iters = NSP / (ks * 32);

  pre_k<<<dim3(320), 256, 0, stream>>>(x, w0, w1, w2, w3, wT, sums);
  gn_apply_k<<<dim3(64,4,4), 256, 0, stream>>>(x, sums, gamma, beta, h_t);
  gemm_qkv_k<<<dim3(64, BB, 2), 256, 0, stream>>>(wT, h_t, q_t, k_t, v, b0, b1, b2);

  if (fused){
    // ph01 = phA (ws), ph23 = phB (ws); d_out untouched until proj_comb.
    attn32_k<<<128*ks, 256, 0, stream>>>(q_t, k_t, v, phA, phB, lbuf, iters, 4*ks);
    proj_comb_k<<<dim3(128, BB), 256, 0, stream>>>(phA, phB, lbuf,
                                                   wT + 3*65536, b3, x, out, ks);
  } else {
    // fallback: ph01 in d_out, ph23 = phA; separate combine + proj.
    ushort* ph01 = (ushort*)d_out;
    attn32_k<<<128*ks, 256, 0, stream>>>(q_t, k_t, v, ph01, phA, lbuf, iters, 4*ks);
    ushort* Oc = k_t;                             // k_t dead after attn
    combine_k<<<dim3(64, 4, BB), 256, 0, stream>>>(ph01, phA, lbuf, Oc, ks);
    gemm_proj_k<<<dim3(256, BB), 256, 0, stream>>>(Oc, wT + 3*65536, b3, x, out);
  }
}

// Round 14
// 206.795 us; speedup vs baseline: 1.0313x; 1.0313x over previous
//
#include <hip/hip_runtime.h>
#include <math.h>

// B=4, C=256, N=H*W=4096, G=32. All inputs/output FLOAT32; bf16 internally.
// out = x + nin3( attn( nin0/1/2( groupnorm(x) ) ) )
//
// R22 == R21 resubmitted verbatim (previous round died to a container
// infrastructure failure before any measurement).
// R21: ATTN_STEP is R19's proven single-__syncthreads form (R20's
// counted-vmcnt was neutral -> drain already covered by tile-ahead prefetch).
// NEW vs R19: partials layout co-designed producer/consumer (R18 pattern):
//   Ph[s][b][qtile(128)][cell(2048)x4ushort], cell=(ct*8+m*2+h)*32+cl
// -- the identity image of each attn lane's registers. Attn epilogue stores
// become 512B-contiguous per wave (was 64-cacheline 8B scatter at c*NSP
// stride); proj_comb/combine keep their loop structure, only the address
// math changes. Bit-identical values. Everything else byte-identical R19.

typedef short short8    __attribute__((ext_vector_type(8)));
typedef ushort ushort8  __attribute__((ext_vector_type(8)));
typedef ushort ushort4v __attribute__((ext_vector_type(4)));
typedef float f32x4     __attribute__((ext_vector_type(4)));
typedef float f32x16    __attribute__((ext_vector_type(16)));

#define BB 4
#define CCH 256
#define NSP 4096
#define TEN ((size_t)BB * NSP * CCH)

__device__ __forceinline__ float b2f(ushort h){
  unsigned int u = ((unsigned int)h) << 16;
  float f; __builtin_memcpy(&f, &u, 4); return f;
}
__device__ __forceinline__ ushort f2b(float f){
  unsigned int u; __builtin_memcpy(&u, &f, 4);
  u += 0x7fffu + ((u >> 16) & 1u);   // RTNE
  return (ushort)(u >> 16);
}
// HW packed f32->bf16 RTNE (identical result to f2b pair, 1 instr vs ~6)
__device__ __forceinline__ unsigned int pk2(float a, float b){
  unsigned int r;
  asm("v_cvt_pk_bf16_f32 %0, %1, %2" : "=&v"(r) : "v"(a), "v"(b));
  return r;
}
// async global->LDS DMA, 16B per lane; LDS dest = wave-uniform base + lane*16
__device__ __forceinline__ void dma16(const void* g, void* l){
  __builtin_amdgcn_global_load_lds((const __attribute__((address_space(1))) void*)g,
                                   (__attribute__((address_space(3))) void*)l,
                                   16, 0, 0);
}

// ------- fused: weight transpose+cast (bx<64) | GN partial sums (bx>=64) -------
__global__ __launch_bounds__(256) void pre_k(const float* __restrict__ x,
                                             const float* __restrict__ w0,
                                             const float* __restrict__ w1,
                                             const float* __restrict__ w2,
                                             const float* __restrict__ w3,
                                             ushort* __restrict__ wT,
                                             float* __restrict__ sums){
  __shared__ ushort tile[64][72];
  __shared__ float red[8];
  const int bxx = blockIdx.x;
  const int t = threadIdx.x;
  if (bxx < 64){
    const int wsel = bxx >> 4, tb = bxx & 15;
    const float* w = (wsel==0) ? w0 : (wsel==1) ? w1 : (wsel==2) ? w2 : w3;
    ushort* dst = wT + (size_t)wsel * 65536;
    const int r0 = (tb >> 2) * 64, c0 = (tb & 3) * 64;
    #pragma unroll
    for (int p = 0; p < 2; p++){
      const int r = p*32 + (t >> 3), cc = (t & 7)*8;
      const float* wr = w + (size_t)(r0 + r)*256 + c0 + cc;
      f32x4 a = *(const f32x4*)wr;
      f32x4 d = *(const f32x4*)(wr + 4);
      #pragma unroll
      for (int j = 0; j < 4; j++){
        tile[r][cc + j]     = f2b(a[j]);
        tile[r][cc + 4 + j] = f2b(d[j]);
      }
    }
    __syncthreads();
    #pragma unroll
    for (int p = 0; p < 2; p++){
      const int r = p*32 + (t >> 3), cc = (t & 7)*8;
      ushort8 ov;
      #pragma unroll
      for (int j = 0; j < 8; j++) ov[j] = tile[cc + j][r];
      *(ushort8*)(dst + (size_t)(c0 + r)*256 + r0 + cc) = ov;
    }
  } else {
    // q = (bg, half): each block sums half a group's 16384 floats
    const int q = bxx - 64;                 // 0..255
    const f32x4* p = (const f32x4*)(x + (size_t)(q >> 1)*32768 + (size_t)(q & 1)*16384);
    float s = 0.f, s2 = 0.f;
    for (int i = t; i < 4096; i += 256){
      f32x4 v = p[i];
      #pragma unroll
      for (int j = 0; j < 4; j++){ s += v[j]; s2 += v[j]*v[j]; }
    }
    #pragma unroll
    for (int off = 32; off >= 1; off >>= 1){
      s  += __shfl_down(s,  off, 64);
      s2 += __shfl_down(s2, off, 64);
    }
    const int w = t >> 6;
    if ((t & 63) == 0){ red[w*2] = s; red[w*2+1] = s2; }
    __syncthreads();
    if (t == 0){
      sums[q*2]   = red[0]+red[2]+red[4]+red[6];
      sums[q*2+1] = red[1]+red[3]+red[5]+red[7];
    }
  }
}

// ------- GN apply (finalizes stats from partial sums) + transpose + cast -------
__global__ __launch_bounds__(256) void gn_apply_k(const float* __restrict__ x,
                                                  const float* __restrict__ sums,
                                                  const float* __restrict__ gamma,
                                                  const float* __restrict__ beta,
                                                  ushort* __restrict__ h_t){
  __shared__ ushort tile[64][72];
  const int b = blockIdx.z, c0 = blockIdx.y*64, n0 = blockIdx.x*64;
  const int t = threadIdx.x;
  #pragma unroll
  for (int p = 0; p < 2; p++){
    const int cl = p*32 + (t >> 3);
    const int nc = (t & 7) * 8;
    const int c = c0 + cl;
    const int bg = b*32 + (c>>3);
    const float S  = sums[bg*4+0] + sums[bg*4+2];
    const float S2 = sums[bg*4+1] + sums[bg*4+3];
    const float mean = S * (1.f/32768.f);
    const float rstd = rsqrtf(fmaxf(S2*(1.f/32768.f) - mean*mean, 0.f) + 1e-6f);
    const float sc = rstd * gamma[c];
    const float sh = beta[c] - mean * sc;
    const float* xr = x + ((size_t)b*CCH + c)*NSP + n0 + nc;
    f32x4 a = *(const f32x4*)xr;
    f32x4 d = *(const f32x4*)(xr + 4);
    #pragma unroll
    for (int j = 0; j < 4; j++){
      tile[nc + j][cl]     = f2b(a[j]*sc + sh);
      tile[nc + 4 + j][cl] = f2b(d[j]*sc + sh);
    }
  }
  __syncthreads();
  #pragma unroll
  for (int p = 0; p < 2; p++){
    const int nl = p*32 + (t >> 3);
    const int cc = (t & 7) * 8;
    ushort8 ov;
    #pragma unroll
    for (int j = 0; j < 8; j++) ov[j] = tile[nl][cc + j];
    *(ushort8*)(h_t + ((size_t)b*NSP + n0 + nl)*CCH + c0 + cc) = ov;
  }
}

// ------------- merged QKV GEMMs: z=0 -> Q&K (Bt staged once, tm loop),
//               z=1 -> V (afr loaded once, tn loop) ---------------------------
// K output layout: Kg[b][tile(n>>5)][g=(m>>3)][key=(n&31)][8ch]   (attn cells)
// V output layout: Vg[b][tile(m>>5)][s=(m>>3)&3][c=n][8key]       (attn cells)
__global__ __launch_bounds__(256) void gemm_qkv_k(const ushort* __restrict__ wT,
                                                  const ushort* __restrict__ h_t,
                                                  ushort* __restrict__ q_t,
                                                  ushort* __restrict__ k_t,
                                                  ushort* __restrict__ vout,
                                                  const float* __restrict__ b0,
                                                  const float* __restrict__ b1,
                                                  const float* __restrict__ b2){
  __shared__ ushort Bt[64*256];
  const int K = 256;
  const long HS = (long)NSP * CCH;
  const int t = threadIdx.x, w = t >> 6, lane = t & 63;
  const int li = lane & 15, quad = lane >> 4;
  const int batch = blockIdx.y;

  if (blockIdx.z == 0){
    const ushort* Bm = h_t + (size_t)batch * HS;
    ushort* out0 = q_t + (size_t)batch * HS;
    ushort* out1 = k_t + (size_t)batch * HS;
    const int nb = blockIdx.x * 64;

    #pragma unroll
    for (int i = 0; i < 8; i++){
      const int id = t + 256*i;
      const int row = id >> 5, gg = id & 31;
      *(ushort8*)&Bt[row*256 + (gg ^ (row & 31))*8] =
        *(const ushort8*)(Bm + (size_t)(nb + row)*K + gg*8);
    }
    __syncthreads();

    for (int tm = 0; tm < 4; tm++){
      const int m0 = tm*64 + w*16;
      short8 afr0[8], afr1[8];
      #pragma unroll
      for (int kk = 0; kk < 8; kk++){
        afr0[kk] = *(const short8*)(wT +         (size_t)(m0 + li)*K + kk*32 + quad*8);
        afr1[kk] = *(const short8*)(wT + 65536 + (size_t)(m0 + li)*K + kk*32 + quad*8);
      }
      #pragma unroll
      for (int nt = 0; nt < 4; nt++){
        f32x4 acc0 = {0.f,0.f,0.f,0.f};
        f32x4 acc1 = {0.f,0.f,0.f,0.f};
        const int n = nb + nt*16 + li;
        const int rowl = nt*16 + li;
        #pragma unroll
        for (int kk = 0; kk < 8; kk++){
          short8 bfr = *(const short8*)&Bt[rowl*256 + ((4*kk + quad) ^ (rowl & 31))*8];
          acc0 = __builtin_amdgcn_mfma_f32_16x16x32_bf16(afr0[kk], bfr, acc0, 0, 0, 0);
          acc1 = __builtin_amdgcn_mfma_f32_16x16x32_bf16(afr1[kk], bfr, acc1, 0, 0, 0);
        }
        float e0[4], e1[4];
        #pragma unroll
        for (int r2 = 0; r2 < 4; r2++){
          e0[r2] = acc0[r2] + b0[m0 + quad*4 + r2];
          e1[r2] = acc1[r2] + b1[m0 + quad*4 + r2];
        }
        uint2 d0; d0.x = pk2(e0[0], e0[1]); d0.y = pk2(e0[2], e0[3]);
        uint2 d1; d1.x = pk2(e1[0], e1[1]); d1.y = pk2(e1[2], e1[3]);
        const int m = m0 + quad*4;
        *(uint2*)(out0 + (size_t)n*256 + m) = d0;                    // Q: n-major
        *(uint2*)(out1 + (size_t)(n >> 5)*8192 + (m >> 3)*256
                       + (n & 31)*8 + (m & 7)) = d1;                 // K: tiled
      }
    }
  } else {
    const ushort* A  = h_t + (size_t)batch * HS;
    const ushort* Bm = wT + 2*65536;
    ushort* OutT = vout + (size_t)batch * HS;
    const int m0 = blockIdx.x*64 + w*16;

    short8 afr[8];
    #pragma unroll
    for (int kk = 0; kk < 8; kk++)
      afr[kk] = *(const short8*)(A + (size_t)(m0 + li)*K + kk*32 + quad*8);

    for (int tn = 0; tn < 4; tn++){
      const int nb = tn*64;
      __syncthreads();
      #pragma unroll
      for (int i = 0; i < 8; i++){
        const int id = t + 256*i;
        const int row = id >> 5, gg = id & 31;
        *(ushort8*)&Bt[row*256 + (gg ^ (row & 31))*8] =
          *(const ushort8*)(Bm + (size_t)(nb + row)*K + gg*8);
      }
      __syncthreads();

      #pragma unroll
      for (int nt = 0; nt < 4; nt++){
        f32x4 acc = {0.f,0.f,0.f,0.f};
        const int n = nb + nt*16 + li;
        const int rowl = nt*16 + li;
        #pragma unroll
        for (int kk = 0; kk < 8; kk++){
          short8 bfr = *(const short8*)&Bt[rowl*256 + ((4*kk + quad) ^ (rowl & 31))*8];
          acc = __builtin_amdgcn_mfma_f32_16x16x32_bf16(afr[kk], bfr, acc, 0, 0, 0);
        }
        const float bn = b2[n];
        float e[4];
        #pragma unroll
        for (int r2 = 0; r2 < 4; r2++) e[r2] = acc[r2] + bn;
        uint2 dv; dv.x = pk2(e[0], e[1]); dv.y = pk2(e[2], e[3]);
        const int m = m0 + quad*4;                                   // spatial key
        *(uint2*)(OutT + (size_t)(m >> 5)*8192 + ((m >> 3) & 3)*2048
                       + (size_t)n*8 + (m & 7)) = dv;                // V: tiled
      }
    }
  }
}

// ---------------- 32x32x16 fixed-M flash attention, full-DMA double-buffer -----
// R19 sync structure (proven); tiled partial store:
// Ph[s][b][qtile][cell], cell=(ct*8+m*2+h)*32+cl, 4 ushorts = q-offsets
// 8m+4h+{0..3} of channel ct*32+cl. Wave stores 512B contiguous.
#define STAGE_KV(KDST, VDST, TILE)                                              \
  _Pragma("unroll")                                                             \
  for (int i_ = 0; i_ < 4; i_++){                                               \
    const int cell_ = (w*4 + i_)*64 + lane;                                     \
    dma16(kb + (size_t)(TILE)*8192 + cell_*8, &(KDST)[(w*4 + i_)*512]);         \
    dma16(vb + (size_t)(TILE)*8192 + cell_*8, &(VDST)[(w*4 + i_)*512]);         \
  }

#define ATTN_STEP(KC, VC, KN, VN, IT)                                           \
  {                                                                             \
    const int it_ = (IT);                                                       \
    const bool more_ = (it_ + 1 < iters);                                       \
    if (more_){                                                                 \
      STAGE_KV(KN, VN, tile0 + it_ + 1);                                        \
    }                                                                           \
    f32x16 sacc = (f32x16)(0.f);                                                \
    _Pragma("unroll")                                                           \
    for (int st = 0; st < 16; st++){                                            \
      short8 kf = *(const short8*)&(KC)[((st*2 + h)*32 + cl)*8];                \
      sacc = __builtin_amdgcn_mfma_f32_32x32x16_bf16(kf, qf[st], sacc, 0, 0, 0);\
    }                                                                           \
    unsigned int grp[4][2];                                                     \
    _Pragma("unroll")                                                           \
    for (int m = 0; m < 4; m++){                                                \
      float p0 = __builtin_amdgcn_exp2f(fminf(sacc[4*m+0]*c1 - M2, 30.f));      \
      float p1 = __builtin_amdgcn_exp2f(fminf(sacc[4*m+1]*c1 - M2, 30.f));      \
      float p2 = __builtin_amdgcn_exp2f(fminf(sacc[4*m+2]*c1 - M2, 30.f));      \
      float p3 = __builtin_amdgcn_exp2f(fminf(sacc[4*m+3]*c1 - M2, 30.f));      \
      l_i += (p0 + p1) + (p2 + p3);                                             \
      grp[m][0] = pk2(p0, p1);                                                  \
      grp[m][1] = pk2(p2, p3);                                                  \
    }                                                                           \
    unsigned int sa0 = h ? grp[0][0] : grp[1][0];                               \
    unsigned int sa1 = h ? grp[0][1] : grp[1][1];                               \
    unsigned int sb0 = h ? grp[2][0] : grp[3][0];                               \
    unsigned int sb1 = h ? grp[2][1] : grp[3][1];                               \
    unsigned int ra0 = __shfl_xor((int)sa0, 32, 64);                            \
    unsigned int ra1 = __shfl_xor((int)sa1, 32, 64);                            \
    unsigned int rb0 = __shfl_xor((int)sb0, 32, 64);                            \
    unsigned int rb1 = __shfl_xor((int)sb1, 32, 64);                            \
    unsigned int f0[4], f1[4];                                                  \
    if (h == 0){                                                                \
      f0[0]=grp[0][0]; f0[1]=grp[0][1]; f0[2]=ra0; f0[3]=ra1;                   \
      f1[0]=grp[2][0]; f1[1]=grp[2][1]; f1[2]=rb0; f1[3]=rb1;                   \
    } else {                                                                    \
      f0[0]=ra0; f0[1]=ra1; f0[2]=grp[1][0]; f0[3]=grp[1][1];                   \
      f1[0]=rb0; f1[1]=rb1; f1[2]=grp[3][0]; f1[3]=grp[3][1];                   \
    }                                                                           \
    short8 pf0, pf1;                                                            \
    __builtin_memcpy(&pf0, f0, 16);                                             \
    __builtin_memcpy(&pf1, f1, 16);                                             \
    _Pragma("unroll")                                                           \
    for (int ct = 0; ct < 8; ct++){                                             \
      short8 v0 = *(const short8*)&(VC)[(h*256 + ct*32 + cl)*8];                \
      short8 v1 = *(const short8*)&(VC)[((2 + h)*256 + ct*32 + cl)*8];          \
      oacc[ct] = __builtin_amdgcn_mfma_f32_32x32x16_bf16(pf0, v0, oacc[ct], 0, 0, 0); \
      oacc[ct] = __builtin_amdgcn_mfma_f32_32x32x16_bf16(pf1, v1, oacc[ct], 0, 0, 0); \
    }                                                                           \
    if (more_) __syncthreads();                                                 \
  }

__global__ __launch_bounds__(256, 2) void attn32_k(const ushort* __restrict__ qg,
                                                   const ushort* __restrict__ kg,
                                                   const ushort* __restrict__ vg,
                                                   ushort* __restrict__ ph01,
                                                   ushort* __restrict__ ph23,
                                                   float* __restrict__ lbuf,
                                                   int iters, int ks4){
  __shared__ ushort KtA[8192], KtB[8192];  // [g(32)][key(32)] x 8 ushort
  __shared__ ushort VtA[8192], VtB[8192];  // [s(4)][c(256)] x 8 ushort

  const int t = threadIdx.x, lane = t & 63;
  const int cl = lane & 31, h = lane >> 5;
  const int bx = blockIdx.x;
  const int qt = bx / ks4;                 // ks4 = 4*ks
  const int r  = bx % ks4;
  const int s  = r >> 2, b = r & 3;
  const int n0 = qt * 128;
  const int w = t >> 6;
  const int qb = n0 + w*32;                // wave's query base
  const int keybase = s * (iters * 32);
  const int tile0 = keybase >> 5;

  const ushort* kb = kg + (size_t)b*NSP*CCH;
  const ushort* vb = vg + (size_t)b*CCH*NSP;

  // Q as B-operand: lane holds q = qb+cl, channels st*16 + h*8 + j
  short8 qf[16];
  {
    const ushort* qrow = qg + ((size_t)b*NSP + qb + cl)*CCH + h*8;
    #pragma unroll
    for (int st = 0; st < 16; st++) qf[st] = *(const short8*)(qrow + st*16);
  }

  f32x16 oacc[8];
  #pragma unroll
  for (int i = 0; i < 8; i++) oacc[i] = (f32x16)(0.f);
  float l_i = 0.f;
  const float c1 = 0.0625f * 1.44269504088896f;   // C^-0.5 * log2(e)
  const float M2 = 24.f;

  // prologue: DMA tile 0 into A buffers (only exposed latency, once)
  STAGE_KV(KtA, VtA, tile0);
  __syncthreads();

  for (int it = 0; it < iters; it += 2){   // iters even (32 or 64)
    ATTN_STEP(KtA, VtA, KtB, VtB, it);
    ATTN_STEP(KtB, VtB, KtA, VtA, it + 1);
  }

  // partial store, TILED: Ph[s][b][qtile][cell(2048) x uint2]
  // cell = (ct*8 + m*2 + h)*32 + cl; uint2 = q-offsets 8m+4h+{0..3}, c=ct*32+cl
  ushort* ps = (s < 2) ? (ph01 + (size_t)s*TEN) : (ph23 + (size_t)(s-2)*TEN);
  ps += (size_t)b * NSP * CCH + (size_t)(qb >> 5) * 8192;
  #pragma unroll
  for (int ct = 0; ct < 8; ct++){
    #pragma unroll
    for (int m = 0; m < 4; m++){
      unsigned int d0 = pk2(oacc[ct][4*m+0], oacc[ct][4*m+1]);
      unsigned int d1 = pk2(oacc[ct][4*m+2], oacc[ct][4*m+3]);
      uint2 dv; dv.x = d0; dv.y = d1;
      const int cell = (ct*8 + m*2 + h)*32 + cl;
      *(uint2*)(ps + cell*4) = dv;
    }
  }
  l_i += __shfl_xor(l_i, 32, 64);
  if (h == 0)
    lbuf[(size_t)s*BB*NSP + (size_t)b*NSP + qb + cl] = l_i;
}

// ---- fused combine + projection: 32q x 256d per block ------------------------
// Reads the TILED partial layout (same loop structure, new address math).
__global__ __launch_bounds__(256) void proj_comb_k(const ushort* __restrict__ ph01,
                                                   const ushort* __restrict__ ph23,
                                                   const float* __restrict__ lbuf,
                                                   const ushort* __restrict__ Bm,
                                                   const float* __restrict__ b3,
                                                   const float* __restrict__ xin,
                                                   float* __restrict__ out, int ks){
  __shared__ ushort At[32*256];            // normalized O tile, swizzled
  __shared__ ushort Bt[64*256];            // w3T d-tile
  const int K = 256;
  const int t = threadIdx.x, w = t >> 6, lane = t & 63;
  const int li = lane & 15, quad = lane >> 4;
  const int q0 = blockIdx.x * 32, b = blockIdx.y;

  // ---- combine phase ----
  const int ql4 = (t & 7) * 4;             // this thread's 4 queries (qoff0)
  const int cs  = t >> 3;                  // 32 c-slices of 8 channels
  const int m_ = ql4 >> 3, h_ = (ql4 >> 2) & 1;
  const size_t tbase = (size_t)b*NSP*CCH + (size_t)blockIdx.x*8192;
  float rl[4];
  #pragma unroll
  for (int j = 0; j < 4; j++){
    float suml = 0.f;
    for (int sp = 0; sp < ks; sp++)
      suml += lbuf[(size_t)sp*BB*NSP + (size_t)b*NSP + q0 + ql4 + j];
    rl[j] = 1.f / suml;
  }
  #pragma unroll
  for (int ci = 0; ci < 8; ci++){
    const int c = cs*8 + ci;
    const int cell = ((c >> 5)*8 + m_*2 + h_)*32 + (c & 31);
    float acc[4] = {0.f, 0.f, 0.f, 0.f};
    for (int sp = 0; sp < ks; sp++){
      const ushort* pp = (sp < 2) ? (ph01 + (size_t)sp*TEN) : (ph23 + (size_t)(sp-2)*TEN);
      ushort4v u = *(const ushort4v*)(pp + tbase + cell*4);
      #pragma unroll
      for (int j = 0; j < 4; j++) acc[j] += b2f(u[j]);
    }
    const int g = c >> 3, co = c & 7;
    #pragma unroll
    for (int j = 0; j < 4; j++){
      const int row = ql4 + j;
      At[row*256 + ((g ^ row) & 31)*8 + co] = f2b(acc[j] * rl[j]);
    }
  }
  __syncthreads();

  // ---- GEMM phase: A from At (wave m-tile = w&1), d-halves by w>>1 ----
  const int mrow = (w & 1)*16 + li;
  short8 afr[8];
  #pragma unroll
  for (int kk = 0; kk < 8; kk++)
    afr[kk] = *(const short8*)&At[mrow*256 + (((4*kk + quad) ^ mrow) & 31)*8];

  xin += (size_t)b * CCH * NSP;
  out += (size_t)b * CCH * NSP;
  for (int tn = 0; tn < 4; tn++){
    __syncthreads();                       // prior Bt readers done
    #pragma unroll
    for (int i = 0; i < 8; i++){
      const int id = t + 256*i;
      const int row = id >> 5, gg = id & 31;
      *(ushort8*)&Bt[row*256 + (gg ^ (row & 31))*8] =
        *(const ushort8*)(Bm + (size_t)(tn*64 + row)*K + gg*8);
    }
    __syncthreads();                       // staged

    #pragma unroll
    for (int s2 = 0; s2 < 2; s2++){
      f32x4 acc = {0.f,0.f,0.f,0.f};
      const int rowb = (w >> 1)*32 + s2*16 + li;   // d row within 64-d tile
      const int d = tn*64 + rowb;
      #pragma unroll
      for (int kk = 0; kk < 8; kk++){
        short8 bfr = *(const short8*)&Bt[rowb*256 + (((4*kk + quad) ^ rowb) & 31)*8];
        acc = __builtin_amdgcn_mfma_f32_16x16x32_bf16(afr[kk], bfr, acc, 0, 0, 0);
      }
      const float bias = b3[d];
      const size_t idx = (size_t)d*NSP + q0 + (w & 1)*16 + quad*4;
      f32x4 xv = *(const f32x4*)(xin + idx);
      f32x4 ov;
      #pragma unroll
      for (int r2 = 0; r2 < 4; r2++) ov[r2] = acc[r2] + bias + xv[r2];
      *(f32x4*)(out + idx) = ov;
    }
  }
}

// ---------------- fallback: combine + proj as separate kernels -----------------
// combine_k updated for the tiled partial layout.
__global__ __launch_bounds__(256) void combine_k(const ushort* __restrict__ ph01,
                                                 const ushort* __restrict__ ph23,
                                                 const float* __restrict__ lbuf,
                                                 ushort* __restrict__ Oc, int ks){
  __shared__ ushort T[64*66];
  const int t = threadIdx.x;
  const int q0 = blockIdx.x * 64, c0 = blockIdx.y * 64, b = blockIdx.z;
  const int ql4 = (t & 15) * 4;            // 0..60 within the 64-q block
  const int cs  = t >> 4;
  const int qtl = ql4 >> 5;                // local qtile (0/1)
  const int qoff = ql4 & 31;
  const int m_ = qoff >> 3, h_ = (qoff >> 2) & 1;
  const size_t tbase = (size_t)b*NSP*CCH + (size_t)((q0 >> 5) + qtl)*8192;
  float rl[4];
  #pragma unroll
  for (int j = 0; j < 4; j++){
    float suml = 0.f;
    for (int sp = 0; sp < ks; sp++)
      suml += lbuf[(size_t)sp*BB*NSP + (size_t)b*NSP + q0 + ql4 + j];
    rl[j] = 1.f / suml;
  }
  #pragma unroll
  for (int ci = 0; ci < 4; ci++){
    const int c = c0 + cs*4 + ci;
    const int cell = ((c >> 5)*8 + m_*2 + h_)*32 + (c & 31);
    float acc[4] = {0.f, 0.f, 0.f, 0.f};
    for (int sp = 0; sp < ks; sp++){
      const ushort* pp = (sp < 2) ? (ph01 + (size_t)sp*TEN) : (ph23 + (size_t)(sp-2)*TEN);
      ushort4v u = *(const ushort4v*)(pp + tbase + cell*4);
      #pragma unroll
      for (int j = 0; j < 4; j++) acc[j] += b2f(u[j]);
    }
    #pragma unroll
    for (int j = 0; j < 4; j++)
      T[(ql4 + j)*66 + (cs*4 + ci)] = f2b(acc[j] * rl[j]);
  }
  __syncthreads();
  const int q2 = t >> 2, ch = (t & 3) * 16;
  ushort8 o0, o1;
  #pragma unroll
  for (int j = 0; j < 8; j++){ o0[j] = T[q2*66 + ch + j]; o1[j] = T[q2*66 + ch + 8 + j]; }
  ushort* dst = Oc + ((size_t)b*NSP + q0 + q2)*CCH + c0 + ch;
  *(ushort8*)dst = o0;
  *(ushort8*)(dst + 8) = o1;
}

__global__ __launch_bounds__(256) void gemm_proj_k(const ushort* __restrict__ A,
                                                   const ushort* __restrict__ Bm,
                                                   const float* __restrict__ b3,
                                                   const float* __restrict__ xin,
                                                   float* __restrict__ out){
  __shared__ ushort Bt[64*256];
  const int K = 256;
  const int t = threadIdx.x, w = t >> 6, lane = t & 63;
  const int li = lane & 15, quad = lane >> 4;
  const int tm = blockIdx.x & 63, tn = blockIdx.x >> 6;
  const int batch = blockIdx.y;
  A   += (size_t)batch * NSP * CCH;
  xin += (size_t)batch * CCH * NSP;
  out += (size_t)batch * CCH * NSP;
  const int m0 = tm*64 + w*16;
  const int nb = tn*64;

  #pragma unroll
  for (int i = 0; i < 8; i++){
    const int id = t + 256*i;
    const int row = id >> 5, gg = id & 31;
    *(ushort8*)&Bt[row*256 + (gg ^ (row & 31))*8] =
      *(const ushort8*)(Bm + (size_t)(nb + row)*K + gg*8);
  }
  short8 afr[8];
  #pragma unroll
  for (int kk = 0; kk < 8; kk++)
    afr[kk] = *(const short8*)(A + (size_t)(m0 + li)*K + kk*32 + quad*8);
  __syncthreads();

  #pragma unroll
  for (int nt = 0; nt < 4; nt++){
    f32x4 acc = {0.f,0.f,0.f,0.f};
    const int d = nb + nt*16 + li;
    const int rowl = nt*16 + li;
    #pragma unroll
    for (int kk = 0; kk < 8; kk++){
      short8 bfr = *(const short8*)&Bt[rowl*256 + ((4*kk + quad) ^ (rowl & 31))*8];
      acc = __builtin_amdgcn_mfma_f32_16x16x32_bf16(afr[kk], bfr, acc, 0, 0, 0);
    }
    const float bias = b3[d];
    const size_t idx = (size_t)d*NSP + m0 + quad*4;
    f32x4 xv = *(const f32x4*)(xin + idx);
    f32x4 ov;
    #pragma unroll
    for (int r = 0; r < 4; r++) ov[r] = acc[r] + bias + xv[r];
    *(f32x4*)(out + idx) = ov;
  }
}

extern "C" void kernel_launch(void* const* d_in, const int* in_sizes, int n_in,
                              void* d_out, int out_size, void* d_ws, size_t ws_size,
                              hipStream_t stream){
  const float* x     = (const float*)d_in[0];
  const float* gamma = (const float*)d_in[1];
  const float* beta  = (const float*)d_in[2];
  const float* w0    = (const float*)d_in[3];
  const float* b0    = (const float*)d_in[4];
  const float* w1    = (const float*)d_in[5];
  const float* b1    = (const float*)d_in[6];
  const float* w2    = (const float*)d_in[7];
  const float* b2    = (const float*)d_in[8];
  const float* w3    = (const float*)d_in[9];
  const float* b3    = (const float*)d_in[10];
  float* out = (float*)d_out;

  ushort* h_t  = (ushort*)d_out;                  // d_out scratch (dead later)
  ushort* q_t = (ushort*)d_ws;
  ushort* k_t = q_t + TEN;
  ushort* v   = k_t + TEN;
  ushort* wT  = v + TEN;                          // 4 x 65536 bf16
  float* sums  = (float*)(wT + 4*65536);          // 512 f32: GN partial sums
  float* lbuf  = sums + 512;                      // disjoint from sums
  ushort* phA = (ushort*)(lbuf + 4*BB*NSP);       // 2 splits (16.8 MB)
  ushort* phB = phA + 2*TEN;                      // 2 more splits (fused only)

  const size_t need4 = ((3*TEN + 4*65536)*2) + (512 + 4*BB*NSP)*4 + 2*TEN*2;
  const size_t need5 = need4 + 2*TEN*2;           // + ph01 in ws
  const int ks = (ws_size >= need4) ? 4 : 2;
  const int fused = (ws_size >= need5) && (ks == 4);
  const int iters = NSP / (ks * 32);

  pre_k<<<dim3(320), 256, 0, stream>>>(x, w0, w1, w2, w3, wT, sums);
  gn_apply_k<<<dim3(64,4,4), 256, 0, stream>>>(x, sums, gamma, beta, h_t);
  gemm_qkv_k<<<dim3(64, BB, 2), 256, 0, stream>>>(wT, h_t, q_t, k_t, v, b0, b1, b2);

  if (fused){
    // ph01 = phA (ws), ph23 = phB (ws); d_out untouched until proj_comb.
    attn32_k<<<128*ks, 256, 0, stream>>>(q_t, k_t, v, phA, phB, lbuf, iters, 4*ks);
    proj_comb_k<<<dim3(128, BB), 256, 0, stream>>>(phA, phB, lbuf,
                                                   wT + 3*65536, b3, x, out, ks);
  } else {
    // fallback: ph01 in d_out, ph23 = phA; separate combine + proj.
    ushort* ph01 = (ushort*)d_out;
    attn32_k<<<128*ks, 256, 0, stream>>>(q_t, k_t, v, ph01, phA, lbuf, iters, 4*ks);
    ushort* Oc = k_t;                             // k_t dead after attn
    combine_k<<<dim3(64, 4, BB), 256, 0, stream>>>(ph01, phA, lbuf, Oc, ks);
    gemm_proj_k<<<dim3(256, BB), 256, 0, stream>>>(Oc, wT + 3*65536, b3, x, out);
  }
}